// Round 1
// baseline (457.753 us; speedup 1.0000x reference)
//
#include <hip/hip_runtime.h>

#define NUM_CELLS 8192
#define COLS 1024

typedef float vf4 __attribute__((ext_vector_type(4)));
// 4-byte-aligned float4 for the odd-offset W' output region (starts at elem 16385)
typedef vf4 uvf4 __attribute__((aligned(4)));

// Pass 1: new_active (out[0..8191]), anomaly (out[16384]), learn-gate flag (ws[0])
__global__ __launch_bounds__(1024) void prep_kernel(
    const float* __restrict__ act_cols, const float* __restrict__ pred,
    const float* __restrict__ prev, float* __restrict__ out,
    float* __restrict__ ws) {
  const int t = threadIdx.x;  // one thread per column, 1024 threads
  const vf4* __restrict__ pred4 = (const vf4*)pred;
  const vf4* __restrict__ prev4 = (const vf4*)prev;

  const vf4 p0 = pred4[t * 2 + 0];
  const vf4 p1 = pred4[t * 2 + 1];
  const vf4 q0 = prev4[t * 2 + 0];
  const vf4 q1 = prev4[t * 2 + 1];

  const float colsum = p0.x + p0.y + p0.z + p0.w + p1.x + p1.y + p1.z + p1.w;
  const bool has_pred = colsum > 0.f;
  const bool active = act_cols[t] > 0.f;

  vf4 o0, o1;
  if (active) {
    if (has_pred) { o0 = p0; o1 = p1; }
    else          { o0 = (vf4){1.f,1.f,1.f,1.f}; o1 = (vf4){1.f,1.f,1.f,1.f}; }
  } else {
    o0 = (vf4){0.f,0.f,0.f,0.f}; o1 = o0;
  }
  ((vf4*)out)[t * 2 + 0] = o0;
  ((vf4*)out)[t * 2 + 1] = o1;

  float nA = active ? 1.f : 0.f;
  float nP = (active && has_pred) ? 1.f : 0.f;
  float ps = q0.x + q0.y + q0.z + q0.w + q1.x + q1.y + q1.z + q1.w;

#pragma unroll
  for (int off = 32; off; off >>= 1) {
    nA += __shfl_down(nA, off);
    nP += __shfl_down(nP, off);
    ps += __shfl_down(ps, off);
  }
  __shared__ float sA[16], sP[16], sS[16];
  const int wid = t >> 6;
  if ((t & 63) == 0) { sA[wid] = nA; sP[wid] = nP; sS[wid] = ps; }
  __syncthreads();
  if (t == 0) {
    float a = 0.f, pp = 0.f, s = 0.f;
    for (int i = 0; i < 16; i++) { a += sA[i]; pp += sP[i]; s += sS[i]; }
    out[2 * NUM_CELLS] = 1.0f - pp / fmaxf(a, 1.0f);  // anomaly
    ws[0] = (s > 0.f) ? 1.f : 0.f;                    // learn gate
  }
}

// Pass 2: fused (connected @ new_active) row-reduction + permanence update.
// One WAVE per row (4 rows per 256-thread block): no LDS, no __syncthreads,
// 32 contiguous float4 per lane for deep load pipelining.
// Nontemporal hints on the W read stream and W' write stream (read-once /
// write-once, 268 MB each) keep L2 for the reused new_active vector.
__global__ __launch_bounds__(256) void fused_kernel(
    const float* __restrict__ W, const float* __restrict__ prev,
    float* __restrict__ out, const float* __restrict__ ws) {
  const int lane = threadIdx.x & 63;
  const int row = (blockIdx.x << 2) | (threadIdx.x >> 6);  // 2048 blocks x 4 waves

  const float coef = prev[row] * ws[0];  // 0 or 1, wave-uniform
  const vf4* __restrict__ Wrow = (const vf4*)(W + (size_t)row * NUM_CELLS);
  const vf4* __restrict__ A = (const vf4*)out;  // new_active lives at out[0..8191]
  uvf4* __restrict__ Wout = (uvf4*)(out + 2 * NUM_CELLS + 1 + (size_t)row * NUM_CELLS);

  float sum = 0.f;
  if (coef > 0.f) {
#pragma unroll 8
    for (int k = 0; k < 32; k++) {
      const int idx = (k << 6) | lane;
      const vf4 w = __builtin_nontemporal_load(&Wrow[idx]);
      const vf4 a = A[idx];
      sum += ((w.x >= 0.5f) ? a.x : 0.f) + ((w.y >= 0.5f) ? a.y : 0.f) +
             ((w.z >= 0.5f) ? a.z : 0.f) + ((w.w >= 0.5f) ? a.w : 0.f);
      vf4 u;
      u.x = fminf(fmaxf(w.x + ((a.x > 0.5f) ? 0.1f : -0.01f), 0.f), 1.f);
      u.y = fminf(fmaxf(w.y + ((a.y > 0.5f) ? 0.1f : -0.01f), 0.f), 1.f);
      u.z = fminf(fmaxf(w.z + ((a.z > 0.5f) ? 0.1f : -0.01f), 0.f), 1.f);
      u.w = fminf(fmaxf(w.w + ((a.w > 0.5f) ? 0.1f : -0.01f), 0.f), 1.f);
      __builtin_nontemporal_store(u, &Wout[idx]);
    }
  } else {
#pragma unroll 8
    for (int k = 0; k < 32; k++) {
      const int idx = (k << 6) | lane;
      const vf4 w = __builtin_nontemporal_load(&Wrow[idx]);
      const vf4 a = A[idx];
      sum += ((w.x >= 0.5f) ? a.x : 0.f) + ((w.y >= 0.5f) ? a.y : 0.f) +
             ((w.z >= 0.5f) ? a.z : 0.f) + ((w.w >= 0.5f) ? a.w : 0.f);
      __builtin_nontemporal_store(w, &Wout[idx]);  // pass-through copy
    }
  }

  // wave-local reduction, result in lane 0 — no LDS, no barrier
#pragma unroll
  for (int off = 32; off; off >>= 1) sum += __shfl_down(sum, off);
  if (lane == 0)
    out[NUM_CELLS + row] = (sum >= 13.0f) ? 1.f : 0.f;  // new_predictive
}

extern "C" void kernel_launch(void* const* d_in, const int* in_sizes, int n_in,
                              void* d_out, int out_size, void* d_ws, size_t ws_size,
                              hipStream_t stream) {
  const float* act_cols = (const float*)d_in[0];  // [1024]
  const float* W = (const float*)d_in[1];         // [8192*8192]
  const float* pred = (const float*)d_in[2];      // [8192]
  const float* prev = (const float*)d_in[3];      // [8192]
  float* out = (float*)d_out;
  float* ws = (float*)d_ws;

  prep_kernel<<<1, 1024, 0, stream>>>(act_cols, pred, prev, out, ws);
  fused_kernel<<<NUM_CELLS / 4, 256, 0, stream>>>(W, prev, out, ws);
}